// Round 1
// baseline (1349.484 us; speedup 1.0000x reference)
//
#include <hip/hip_runtime.h>
#include <stdint.h>
#include <math.h>

#define BB 8
#define NN 16384
#define CC 13
#define GG 512
#define KK 32

#define NEIGH_ELEMS (BB*GG*KK*CC)   // 1,703,936

// ---------------------------------------------------------------------------
// DPP wave(64) arg-reductions: 6 VALU stages, result valid in LANE 63 only.
// row_shr:1/2/4/8 accumulate within each 16-lane row (lane 15/31/47/63 hold
// their row's reduction), then row_bcast:15 merges row0->row1 / row2->row3,
// row_bcast:31 merges the halves -> lane 63 covers all 64 lanes.
// bound_ctrl=false with old=self => invalid source lanes combine with
// themselves, which is a no-op for an idempotent combine. The combine
// (strict compare, lower-flat-index tiebreak) is commutative+associative,
// so this reduction tree is exact. DPP runs on the VALU pipe (~4-8 cyc/op)
// vs ds_swizzle's ~60-120 cyc DS-pipe latency -> removes the ~1 Kcyc
// dependent shuffle chain from every FPS step / KNN extraction round.
// ---------------------------------------------------------------------------
__device__ __forceinline__ void wave_argmax_dpp(float& v, int& p) {
    int vi = __float_as_int(v);
    int pi = p;
#define ARGMAX_STAGE(CTRL)                                                   \
    {                                                                        \
        int nv = __builtin_amdgcn_update_dpp(vi, vi, CTRL, 0xF, 0xF, false); \
        int np = __builtin_amdgcn_update_dpp(pi, pi, CTRL, 0xF, 0xF, false); \
        float a = __int_as_float(nv);                                        \
        float b = __int_as_float(vi);                                        \
        if (a > b || (a == b && np < pi)) { vi = nv; pi = np; }              \
    }
    ARGMAX_STAGE(0x111)  // row_shr:1
    ARGMAX_STAGE(0x112)  // row_shr:2
    ARGMAX_STAGE(0x114)  // row_shr:4
    ARGMAX_STAGE(0x118)  // row_shr:8
    ARGMAX_STAGE(0x142)  // row_bcast:15
    ARGMAX_STAGE(0x143)  // row_bcast:31
#undef ARGMAX_STAGE
    v = __int_as_float(vi);
    p = pi;
}

__device__ __forceinline__ void wave_argmin_dpp(float& v, int& p) {
    int vi = __float_as_int(v);
    int pi = p;
#define ARGMIN_STAGE(CTRL)                                                   \
    {                                                                        \
        int nv = __builtin_amdgcn_update_dpp(vi, vi, CTRL, 0xF, 0xF, false); \
        int np = __builtin_amdgcn_update_dpp(pi, pi, CTRL, 0xF, 0xF, false); \
        float a = __int_as_float(nv);                                        \
        float b = __int_as_float(vi);                                        \
        if (a < b || (a == b && np < pi)) { vi = nv; pi = np; }              \
    }
    ARGMIN_STAGE(0x111)  // row_shr:1
    ARGMIN_STAGE(0x112)  // row_shr:2
    ARGMIN_STAGE(0x114)  // row_shr:4
    ARGMIN_STAGE(0x118)  // row_shr:8
    ARGMIN_STAGE(0x142)  // row_bcast:15
    ARGMIN_STAGE(0x143)  // row_bcast:31
#undef ARGMIN_STAGE
    v = __int_as_float(vi);
    p = pi;
}

// ---------------------------------------------------------------------------
// Pack: x[B,N,13] (fp32) -> f32 SoA planes px,py,pz (channels 4..6).
// ---------------------------------------------------------------------------
__global__ void pack_kernel(const float* __restrict__ x,
                            float* __restrict__ px, float* __restrict__ py,
                            float* __restrict__ pz) {
    int i = blockIdx.x * blockDim.x + threadIdx.x;
    if (i >= BB * NN) return;
    const float* p = x + (size_t)i * CC + 4;
    px[i] = p[0]; py[i] = p[1]; pz[i] = p[2];
}

// ---------------------------------------------------------------------------
// FPS v4: one block (512 threads) per batch, 32 points/thread, coords PINNED
// in VGPRs via empty asm (R6/R7 post-mortem: compiler rematerialized the
// global loads every step -> ~3K cyc/step of L1 traffic). One barrier per
// step (parity partials, redundant 8-entry scan). Next center fetched via
// scalar loads (readfirstlane). fp32 math verbatim (bit-exact).
// v4 change: wave argmax via DPP (VALU pipe) instead of the 12-op
// ds_swizzle butterfly; local best index bi (inline-const cndmask) instead
// of per-point flat-pos materialization.
// ---------------------------------------------------------------------------
__global__ __launch_bounds__(512, 2) void fps_kernel(const float* __restrict__ px,
                                                     const float* __restrict__ py,
                                                     const float* __restrict__ pz,
                                                     float* __restrict__ centers) {
    const int b = blockIdx.x;
    const int t = threadIdx.x;
    const float* PX = px + b * NN;
    const float* PY = py + b * NN;
    const float* PZ = pz + b * NN;

    float X[32], Y[32], Z[32], MD[32];
#pragma unroll
    for (int i = 0; i < 32; ++i) {
        int pos = t + (i << 9);
        X[i] = PX[pos]; Y[i] = PY[pos]; Z[i] = PZ[pos];
        MD[i] = 1e10f;   // init_d = 10000000000.0
        // Pin: mark values as asm-modified so the loads cannot be
        // rematerialized inside the step loop. Forces VGPR residency.
        asm volatile("" : "+v"(X[i]), "+v"(Y[i]), "+v"(Z[i]));
    }

    __shared__ float s_v[2][8];
    __shared__ int   s_p[2][8];

    int wp = 0;   // current center index (uniform across block)
    if (t == 0) {
        float* oc = centers + (size_t)b * GG * 3;
        oc[0] = PX[0]; oc[1] = PY[0]; oc[2] = PZ[0];
    }

    for (int g = 1; g < GG; ++g) {
        // scalar broadcast load of current center coords (uniform index)
        int swp = __builtin_amdgcn_readfirstlane(wp);
        float lx = PX[swp], ly = PY[swp], lz = PZ[swp];
        float bv = -1.0f;
        int bi = 0;   // local best index 0..31 (inline-const cndmask)
#pragma unroll
        for (int i = 0; i < 32; ++i) {
            float e0 = __fsub_rn(X[i], lx);
            float e1 = __fsub_rn(Y[i], ly);
            float e2 = __fsub_rn(Z[i], lz);
            float d  = __fadd_rn(__fadd_rn(__fmul_rn(e0, e0), __fmul_rn(e1, e1)),
                                 __fmul_rn(e2, e2));
            float m = fminf(MD[i], d);   // np.minimum
            MD[i] = m;
            // ascending-index scan + strict '>' keeps lowest index on ties
            if (m > bv) { bv = m; bi = i; }
        }
        int bp = t + (bi << 9);   // flat pos; ascending i == ascending pos
        // wave(64) DPP argmax, tie -> lower flat index; result in lane 63
        wave_argmax_dpp(bv, bp);
        int par = g & 1;
        if ((t & 63) == 63) { s_v[par][t >> 6] = bv; s_p[par][t >> 6] = bp; }
        __syncthreads();
        // redundant scan of 8 partials by every thread (LDS broadcast reads)
        float wv = s_v[par][0]; int wi = s_p[par][0];
#pragma unroll
        for (int q = 1; q < 8; ++q) {
            float qv = s_v[par][q]; int qp = s_p[par][q];
            if (qv > wv || (qv == wv && qp < wi)) { wv = qv; wi = qp; }
        }
        wp = wi;
        if (t == 0) {
            float* oc = centers + ((size_t)b * GG + g) * 3;
            oc[0] = PX[wp]; oc[1] = PY[wp]; oc[2] = PZ[wp];
        }
        // no second barrier: parity buffer isolates next round's writes
    }
}

// ---------------------------------------------------------------------------
// KNN v3 + gather (R7 structure, unchanged math) + XCD swizzle: batch b's 512
// blocks map to one XCD (blockIdx round-robins XCDs by %8) so the 196 KB SoA
// stays L2-resident per XCD.
// v3 change: per-round wave argmin via DPP instead of ds_swizzle butterfly.
// ---------------------------------------------------------------------------
__global__ __launch_bounds__(256, 8) void knn_kernel(const float* __restrict__ px,
                                                     const float* __restrict__ py,
                                                     const float* __restrict__ pz,
                                                     const float* __restrict__ x,
                                                     const float* __restrict__ centers,
                                                     float* __restrict__ out) {
    const int blk = blockIdx.x;
    const int bg  = ((blk & 7) << 9) | (blk >> 3);   // batch = blk&7 -> one XCD
    const int b   = bg >> 9;
    const int t   = threadIdx.x;

    const float* ctr = centers + (size_t)bg * 3;
    float cx = ctr[0], cy = ctr[1], cz = ctr[2];
    float cc2 = __fadd_rn(__fadd_rn(__fmul_rn(cx, cx), __fmul_rn(cy, cy)),
                          __fmul_rn(cz, cz));

    const float* PX = px + b * NN;
    const float* PY = py + b * NN;
    const float* PZ = pz + b * NN;

    float k1 = INFINITY, k2 = INFINITY;
    int   p1 = 0x7fffffff, p2 = 0x7fffffff;
    uint64_t mask = 0;   // consumed elements of my 64-pt chunk

#pragma unroll 4
    for (int i = 0; i < 64; ++i) {
        int pos = (i << 8) + t;           // coalesced
        float ax = PX[pos], ay = PY[pos], az = PZ[pos];
        float pp2 = __fadd_rn(__fadd_rn(__fmul_rn(ax, ax), __fmul_rn(ay, ay)),
                              __fmul_rn(az, az));
        float dot = fmaf(cz, az, fmaf(cy, ay, __fmul_rn(cx, ax)));
        float d2  = __fsub_rn(__fadd_rn(cc2, pp2), __fmul_rn(2.0f, dot));
        // ascending pos scan, strict '<': ties keep lower pos
        if (d2 < k1)      { k2 = k1; p2 = p1; k1 = d2; p1 = pos; }
        else if (d2 < k2) { k2 = d2; p2 = pos; }
    }

    __shared__ float s_v[2][4];
    __shared__ int   s_p[2][4];
    __shared__ int   s_chosen[KK];

    for (int j = 0; j < KK; ++j) {
        float v = k1; int vp = p1;
        // wave(64) DPP argmin, tie -> lower pos; result in lane 63
        wave_argmin_dpp(v, vp);
        int par = j & 1;
        if ((t & 63) == 63) { s_v[par][t >> 6] = v; s_p[par][t >> 6] = vp; }
        __syncthreads();
        // redundant scan of 4 partials by every thread
        float wv = s_v[par][0]; int wp = s_p[par][0];
#pragma unroll
        for (int q = 1; q < 4; ++q) {
            float qv = s_v[par][q]; int qp = s_p[par][q];
            if (qv < wv || (qv == wv && qp < wp)) { wv = qv; wp = qp; }
        }
        if (t == 0) s_chosen[j] = wp;
        if ((wp & 255) == t) {
            // I owned the extracted point: mark consumed, promote second
            mask |= 1ull << (wp >> 8);
            k1 = k2; p1 = p2;
            k2 = INFINITY; p2 = 0x7fffffff;
            if (p1 == 0x7fffffff && mask != 0xffffffffffffffffull) {
                // top-2 exhausted (rare): rebuild from unmasked points,
                // reloading coords from global; d2 bit-identical
                k1 = INFINITY;
#pragma unroll 1
                for (int i = 0; i < 64; ++i) {
                    if ((mask >> i) & 1ull) continue;
                    int pos = (i << 8) + t;
                    float ax = PX[pos], ay = PY[pos], az = PZ[pos];
                    float pp2 = __fadd_rn(__fadd_rn(__fmul_rn(ax, ax), __fmul_rn(ay, ay)),
                                          __fmul_rn(az, az));
                    float dot = fmaf(cz, az, fmaf(cy, ay, __fmul_rn(cx, ax)));
                    float d2  = __fsub_rn(__fadd_rn(cc2, pp2), __fmul_rn(2.0f, dot));
                    if (d2 < k1)      { k2 = k1; p2 = p1; k1 = d2; p1 = pos; }
                    else if (d2 < k2) { k2 = d2; p2 = pos; }
                }
            }
        }
        // no second barrier: parity buffer isolates next round's writes
    }
    __syncthreads();   // s_chosen visibility for gather

    // gather: 32 neighbors x 13 channels; subtract center from ch 4..6
    for (int v = t; v < KK * CC; v += 256) {
        int j = v / CC, c = v - j * CC;
        int pt = s_chosen[j] & (NN - 1);   // safety clamp (no-op when correct)
        float val = x[((size_t)b * NN + pt) * CC + c];
        if (c >= 4 && c < 7) {
            float cs = (c == 4) ? cx : ((c == 5) ? cy : cz);
            val = __fsub_rn(val, cs);
        }
        out[((size_t)bg * KK + j) * CC + c] = val;
    }
}

extern "C" void kernel_launch(void* const* d_in, const int* in_sizes, int n_in,
                              void* d_out, int out_size, void* d_ws, size_t ws_size,
                              hipStream_t stream) {
    const float* x = (const float*)d_in[0];
    float* out = (float*)d_out;
    float* centers = out + NEIGH_ELEMS;   // output 1 follows output 0, flat

    float* px = (float*)d_ws;
    float* py = px + BB * NN;
    float* pz = py + BB * NN;

    pack_kernel<<<(BB * NN + 255) / 256, 256, 0, stream>>>(x, px, py, pz);
    fps_kernel<<<BB, 512, 0, stream>>>(px, py, pz, centers);
    knn_kernel<<<BB * GG, 256, 0, stream>>>(px, py, pz, x, centers, out);
}